// Round 5
// baseline (5250.126 us; speedup 1.0000x reference)
//
#include <hip/hip_runtime.h>

// Problem constants (reference: T=512, N=256, H=256, HR=64, WC=128, V=64)
#define TSTEPS 512
#define NBATCH 256
#define HID    256
#define TCHUNK 64
#define NCHUNK 8

typedef __attribute__((ext_vector_type(8))) short bf16x8;
typedef __attribute__((ext_vector_type(4))) float f32x4;

__device__ __forceinline__ unsigned short f2b(float x) {
    union { float f; unsigned int u; } c; c.f = x;
    unsigned int u = c.u;
    return (unsigned short)((u + 0x7fffu + ((u >> 16) & 1u)) >> 16);
}

__device__ __forceinline__ void gload_lds16(const float* g, float* l) {
    __builtin_amdgcn_global_load_lds(
        (const __attribute__((address_space(1))) unsigned int*)g,
        (__attribute__((address_space(3))) unsigned int*)l,
        16, 0, 0);
}

// ---------------------------------------------------------------------------
// Generic GEMM: C[M,N] = act(A[M,K] @ B + bias), bf16 MFMA, fp32 in/out.
// (unchanged — verified correct)
// ---------------------------------------------------------------------------
template<bool TRANS_B, int ACT>
__global__ __launch_bounds__(256) void gemm_f32(
    const float* __restrict__ A, long lda, long sA,
    const float* __restrict__ B, long ldb, long sB,
    const float* __restrict__ bias,
    float* __restrict__ C, long ldc, long sC,
    int M, int N, int K)
{
    __shared__ __align__(16) unsigned short As[64][32];  // [m][k] bf16
    __shared__ __align__(16) unsigned short Bs[64][32];  // [n][k] bf16
    const int z = blockIdx.z;
    A += (long)z * sA; B += (long)z * sB; C += (long)z * sC;
    const int n0 = blockIdx.x * 64, m0 = blockIdx.y * 64;
    const int tid  = threadIdx.x;
    const int lane = tid & 63, w = tid >> 6;
    const int wr = (w >> 1) * 32, wc = (w & 1) * 32;

    f32x4 acc[2][2];
#pragma unroll
    for (int i = 0; i < 2; i++)
#pragma unroll
        for (int j = 0; j < 2; j++) acc[i][j] = (f32x4){0.f, 0.f, 0.f, 0.f};

    for (int k0 = 0; k0 < K; k0 += 32) {
        {   // stage A tile: 64 rows x 32 k
            const int r = tid >> 2, ck = (tid & 3) << 3;
            const float* s = A + (long)(m0 + r) * lda + k0 + ck;
            float4 v0 = *(const float4*)s, v1 = *(const float4*)(s + 4);
            unsigned short* d = &As[r][ck];
            d[0] = f2b(v0.x); d[1] = f2b(v0.y); d[2] = f2b(v0.z); d[3] = f2b(v0.w);
            d[4] = f2b(v1.x); d[5] = f2b(v1.y); d[6] = f2b(v1.z); d[7] = f2b(v1.w);
        }
        if (TRANS_B) {  // B stored (N,K)
            const int r = tid >> 2, ck = (tid & 3) << 3;
            const float* s = B + (long)(n0 + r) * ldb + k0 + ck;
            float4 v0 = *(const float4*)s, v1 = *(const float4*)(s + 4);
            unsigned short* d = &Bs[r][ck];
            d[0] = f2b(v0.x); d[1] = f2b(v0.y); d[2] = f2b(v0.z); d[3] = f2b(v0.w);
            d[4] = f2b(v1.x); d[5] = f2b(v1.y); d[6] = f2b(v1.z); d[7] = f2b(v1.w);
        } else {        // B stored (K,N): scatter-transpose
            const int kk = tid >> 3, cn = (tid & 7) << 3;
            const float* s = B + (long)(k0 + kk) * ldb + n0 + cn;
            float4 v0 = *(const float4*)s, v1 = *(const float4*)(s + 4);
            Bs[cn + 0][kk] = f2b(v0.x); Bs[cn + 1][kk] = f2b(v0.y);
            Bs[cn + 2][kk] = f2b(v0.z); Bs[cn + 3][kk] = f2b(v0.w);
            Bs[cn + 4][kk] = f2b(v1.x); Bs[cn + 5][kk] = f2b(v1.y);
            Bs[cn + 6][kk] = f2b(v1.z); Bs[cn + 7][kk] = f2b(v1.w);
        }
        __syncthreads();
        const int q8 = (lane >> 4) << 3;
        bf16x8 a0 = *(const bf16x8*)&As[wr +      (lane & 15)][q8];
        bf16x8 a1 = *(const bf16x8*)&As[wr + 16 + (lane & 15)][q8];
        bf16x8 b0 = *(const bf16x8*)&Bs[wc +      (lane & 15)][q8];
        bf16x8 b1 = *(const bf16x8*)&Bs[wc + 16 + (lane & 15)][q8];
        acc[0][0] = __builtin_amdgcn_mfma_f32_16x16x32_bf16(a0, b0, acc[0][0], 0, 0, 0);
        acc[0][1] = __builtin_amdgcn_mfma_f32_16x16x32_bf16(a0, b1, acc[0][1], 0, 0, 0);
        acc[1][0] = __builtin_amdgcn_mfma_f32_16x16x32_bf16(a1, b0, acc[1][0], 0, 0, 0);
        acc[1][1] = __builtin_amdgcn_mfma_f32_16x16x32_bf16(a1, b1, acc[1][1], 0, 0, 0);
        __syncthreads();
    }
    const int cq = lane >> 4, cc = lane & 15;
#pragma unroll
    for (int i = 0; i < 2; i++)
#pragma unroll
        for (int j = 0; j < 2; j++) {
#pragma unroll
            for (int rg = 0; rg < 4; rg++) {
                int row = m0 + wr + i * 16 + cq * 4 + rg;
                int col = n0 + wc + j * 16 + cc;
                float v = acc[i][j][rg];
                if (bias) v += bias[col];
                if (ACT == 1) v = v > 0.f ? v : 0.f;
                C[(long)row * ldc + col] = v;
            }
        }
}

// ---------------------------------------------------------------------------
// Helpers
// ---------------------------------------------------------------------------
__global__ void combine_bias(const float* a0, const float* b0,
                             const float* a1, const float* b1,
                             const float* a2, const float* b2,
                             float* o0, float* o1, float* o2)
{
    int i = blockIdx.x * 256 + threadIdx.x;   // 0..767
    o0[i] = a0[i] + b0[i];
    o1[i] = a1[i] + b1[i];
    o2[i] = a2[i] + b2[i];
}

__global__ void seq_major(const float* __restrict__ M, float* __restrict__ Mseq)
{   // M (n,s,256) -> Mseq (s,n,256)
    int b = blockIdx.x;               // s*256+n
    int s = b >> 8, n = b & 255;
    int t = threadIdx.x;
    Mseq[(long)b * 256 + t] = M[((long)n * 64 + s) * 256 + t];
}

// ---------------------------------------------------------------------------
// pack_w: pre-pack Whh (256,768) into the exact per-wave MFMA B-fragment
// layout the 4-wave scan consumes, in bf16. Chunk index:
//   chunk = ((w*12 + f)*8 + kt)*64 + lane,  f = g*4+hh (g<3, hh<4), w<4
//   lane = q*16+c
//   PK[chunk][j] = bf16( Whh[(kt*32 + q*8 + j) * 768 + g*256 + w*64 + hh*16 + c] )
// One 16B store per thread; scan loads Bf[f][kt] = PK[...] fully coalesced.
// Total per matrix: 24576 chunks * 16B = 384 KB.
// ---------------------------------------------------------------------------
__global__ __launch_bounds__(256) void pack_w(
    const float* __restrict__ Wf, const float* __restrict__ Wb, const float* __restrict__ Wc,
    unsigned short* __restrict__ Pf, unsigned short* __restrict__ Pb, unsigned short* __restrict__ Pc)
{
    int chunk = blockIdx.x * 256 + threadIdx.x;      // 0..24575
    const float* W = (blockIdx.y == 0) ? Wf : ((blockIdx.y == 1) ? Wb : Wc);
    unsigned short* P = (blockIdx.y == 0) ? Pf : ((blockIdx.y == 1) ? Pb : Pc);
    int lane = chunk & 63;
    int kt   = (chunk >> 6) & 7;
    int f    = (chunk >> 9) % 12;
    int w    = chunk / 6144;
    int g = f >> 2, hh = f & 3;
    int c = lane & 15, q = lane >> 4;
    int col = g * 256 + w * 64 + hh * 16 + c;
    int k0  = kt * 32 + q * 8;
    unsigned int v[8];
#pragma unroll
    for (int j = 0; j < 8; j++) v[j] = f2b(W[(long)(k0 + j) * 768 + col]);
    uint4 o;
    o.x = v[0] | (v[1] << 16); o.y = v[2] | (v[3] << 16);
    o.z = v[4] | (v[5] << 16); o.w = v[6] | (v[7] << 16);
    *(uint4*)&P[(long)chunk * 8] = o;
}

__global__ void build_x(const float* __restrict__ values, const float* __restrict__ Mbuf,
                        const int* __restrict__ actions, const int* __restrict__ a0,
                        float* __restrict__ Xc, int t0)
{   // Xc row (tl*256+n) = [values[t,n,0:64], M[n, a_prev(t,n), 0:256]]
    int m = blockIdx.x;               // tl*256+n
    int tl = m >> 8, n = m & 255;
    int t = t0 + tl;
    int c = threadIdx.x;              // 0..319
    float v;
    if (c < 64) {
        v = values[((long)t * 256 + n) * 64 + c];
    } else {
        int ap = (t == 0) ? a0[n] : actions[(long)(t - 1) * 256 + n];
        v = Mbuf[((long)n * 64 + ap) * 256 + (c - 64)];
    }
    Xc[(long)m * 320 + c] = v;
}

// ---------------------------------------------------------------------------
// Weight-stationary MFMA GRU scan, v5: fused step for MFMA/VALU overlap.
// 4 waves (256 threads), 1 wave/SIMD, 512-reg unified budget.
// v4 post-mortem: step phases serialized on alternating pipes (MFMA pipe
// ~1860 cyc/SIMD idle while gates ran, and vice versa); the inter-pass
// asm memory fences forbade compiler overlap. v5 removes the fences and
// holds ALL 12 accumulator chains live:
//   Bf 384 + acc 48 + hreg 16 + a-frag ~8 + ptrs/temps ~40  ~= 496 <= 512.
// A-frags are read ONCE per step (8 ds_read_b128, reused by all 12 tiles,
// was 32 reads in v4). MFMAs issue as 12 independent 8-deep chains; gate
// VALU for early tiles runs under the MFMA pipe tail (same-wave co-issue).
// Single counted barrier per step: vmcnt(16) forces the 12 gi prefetch
// loads complete while the 16 output stores stay in flight.
// ---------------------------------------------------------------------------
template<int KGRU>
__global__ __launch_bounds__(256, 1) void scan_mfma(
    const float* __restrict__ gi0, const float* __restrict__ gi1,
    const unsigned short* __restrict__ PK0, const unsigned short* __restrict__ PK1,
    const float* __restrict__ h_init,   // null-equivalent for KGRU (zeros)
    float* __restrict__ outp,           // main: Hallc ; kgru: Kbuf
    float* __restrict__ h_state,        // main only
    int steps)
{
    __shared__ __align__(16) unsigned short hbuf[2][16][264];  // bf16 h, dbuf
    __shared__ __align__(16) float gibuf[2][16 * 772];         // gate inputs, dbuf

    const int tid = threadIdx.x;
    const int w = tid >> 6, lane = tid & 63;
    const int q = lane >> 4, c = lane & 15, q8 = q << 3;
    const int n0 = blockIdx.x * 16;
    const int d = KGRU ? blockIdx.y : 0;
    const float* gi = d ? gi1 : gi0;
    const unsigned short* PK = d ? PK1 : PK0;
    const int wcol = w * 64;

    // ---- one-time: weight B-fragments, straight 16B coalesced loads ----
    bf16x8 Bf[12][8];
#pragma unroll
    for (int f = 0; f < 12; f++)
#pragma unroll
        for (int kt = 0; kt < 8; kt++)
            Bf[f][kt] = *(const bf16x8*)&PK[(((long)(w * 12 + f) * 8 + kt) * 64 + lane) * 8];

    // ---- h init: registers (C-layout) + bf16 staging into hbuf[1] ----
    f32x4 hreg[4];
#pragma unroll
    for (int hh = 0; hh < 4; hh++)
#pragma unroll
        for (int rg = 0; rg < 4; rg++) {
            float v = 0.f;
            if (!KGRU) v = h_init[(long)(n0 + q * 4 + rg) * 256 + wcol + hh * 16 + c];
            hreg[hh][rg] = v;
            hbuf[1][q * 4 + rg][wcol + hh * 16 + c] = f2b(v);
        }

    // ---- hoisted pointers ----
    const int row0 = KGRU ? (d ? 63 : 0) : 0;
    const long gi_stride = KGRU ? (d ? -196608L : 196608L) : 196608L;
    const float* gsrc = gi + ((long)row0 * 256 + n0) * 768;
    float* optr[4];
    long ostride;
    if (KGRU) {
        ostride = d ? -512L : 512L;
#pragma unroll
        for (int rg = 0; rg < 4; rg++)
            optr[rg] = outp + ((long)(n0 + q * 4 + rg) * 64 + row0) * 512 + d * 256 + wcol + c;
    } else {
        ostride = 65536L;
#pragma unroll
        for (int rg = 0; rg < 4; rg++)
            optr[rg] = outp + (long)(n0 + q * 4 + rg) * 256 + wcol + c;
    }

    // ---- prologue: prefetch gi[0] -> gibuf[0] (48 x 1KB, 12 per wave) ----
#pragma unroll
    for (int i = 0; i < 12; i++) {
        int idx = w * 12 + i;             // 0..47
        int r = idx / 3, ch = idx % 3;    // 16 rows x 3 chunks of 256 floats
        gload_lds16(gsrc + (long)r * 768 + ch * 256 + lane * 4,
                    &gibuf[0][r * 772 + ch * 256]);
    }
    __syncthreads();   // full drain: gi[0] + hbuf[1] visible

    for (int s = 0; s < steps; s++) {
        const int cur = s & 1;

        // ---- P1: issue gi prefetch for step s+1 into gibuf[cur^1] ----
        if (s + 1 < steps) {
            const float* src = gsrc + gi_stride;
#pragma unroll
            for (int i = 0; i < 12; i++) {
                int idx = w * 12 + i;
                int r = idx / 3, ch = idx % 3;
                gload_lds16(src + (long)r * 768 + ch * 256 + lane * 4,
                            &gibuf[cur ^ 1][r * 772 + ch * 256]);
            }
        }
        gsrc += gi_stride;
        // pin: all P1 loads issue before any later vmem (exact vmcnt counting)
        asm volatile("" ::: "memory");

        const unsigned short* hrd = &hbuf[cur ^ 1][0][0];
        const float* gp = &gibuf[cur][(q * 4) * 772 + wcol + c];
        unsigned short* hwr = &hbuf[cur][q * 4][wcol + c];

        // ---- P2: all 12 MFMA chains, fused (A-frags read once) ----
        f32x4 acc[12];
#pragma unroll
        for (int t = 0; t < 12; t++) acc[t] = (f32x4){0.f, 0.f, 0.f, 0.f};
#pragma unroll
        for (int kt = 0; kt < 8; kt++) {
            bf16x8 a = *(const bf16x8*)&hrd[c * 264 + kt * 32 + q8];
#pragma unroll
            for (int t = 0; t < 12; t++)
                acc[t] = __builtin_amdgcn_mfma_f32_16x16x32_bf16(a, Bf[t][kt], acc[t], 0, 0, 0);
        }

        // ---- P3: gates + state update + staging + stores (NO fences:
        //      compiler overlaps early-tile VALU with MFMA pipe tail) ----
#pragma unroll
        for (int hh = 0; hh < 4; hh++) {
#pragma unroll
            for (int rg = 0; rg < 4; rg++) {
                float gr = gp[rg * 772 +       hh * 16];
                float gz = gp[rg * 772 + 256 + hh * 16];
                float gn = gp[rg * 772 + 512 + hh * 16];
                float r  = __builtin_amdgcn_rcpf(1.f + __expf(-(gr + acc[0 + hh][rg])));
                float zg = __builtin_amdgcn_rcpf(1.f + __expf(-(gz + acc[4 + hh][rg])));
                float nn = 1.f - 2.f * __builtin_amdgcn_rcpf(1.f + __expf(2.f * (gn + r * acc[8 + hh][rg])));
                float hv = (1.f - zg) * nn + zg * hreg[hh][rg];
                hreg[hh][rg] = hv;
                hwr[rg * 264 + hh * 16] = f2b(hv);
                optr[rg][hh * 16] = hv;
            }
        }

#pragma unroll
        for (int rg = 0; rg < 4; rg++) optr[rg] += ostride;

        // ---- single counted barrier: 12 loads forced done, 16 stores fly ----
        asm volatile("s_waitcnt vmcnt(16) lgkmcnt(0)" ::: "memory");
        __builtin_amdgcn_sched_barrier(0);
        __builtin_amdgcn_s_barrier();
        __builtin_amdgcn_sched_barrier(0);
    }

    if (!KGRU) {
#pragma unroll
        for (int hh = 0; hh < 4; hh++)
#pragma unroll
            for (int rg = 0; rg < 4; rg++)
                h_state[(long)(n0 + q * 4 + rg) * 256 + wcol + hh * 16 + c] = hreg[hh][rg];
    }
}

// ---------------------------------------------------------------------------
// Epilogue: per (t,n) write a, v=critic(h), h copy, softmax(logits).
// ---------------------------------------------------------------------------
__global__ __launch_bounds__(64) void epilogue_k(
    const float* __restrict__ Hallc, const float* __restrict__ Lc,
    const int* __restrict__ actions,
    const float* __restrict__ critic_W, const float* __restrict__ critic_b,
    float* __restrict__ out, int t0)
{
    int m = blockIdx.x;               // tl*256+n
    int tl = m >> 8, n = m & 255;
    int t = t0 + tl;
    int j = threadIdx.x;              // 0..63
    long o = ((long)t * 256 + n) * 322;
    const float* h = Hallc + (long)m * 256;
    float part = 0.f;
#pragma unroll
    for (int i = 0; i < 4; i++) {
        float hv = h[j + 64 * i];
        out[o + 2 + j + 64 * i] = hv;
        part += hv * critic_W[j + 64 * i];
    }
    for (int off = 32; off > 0; off >>= 1) part += __shfl_down(part, off);
    if (j == 0) {
        out[o]     = (float)actions[(long)t * 256 + n];
        out[o + 1] = part + critic_b[0];
    }
    float x = Lc[(long)m * 64 + j];
    float mx = x;
    for (int off = 32; off > 0; off >>= 1) mx = fmaxf(mx, __shfl_down(mx, off));
    mx = __shfl(mx, 0);
    float e = __expf(x - mx);
    float ssum = e;
    for (int off = 32; off > 0; off >>= 1) ssum += __shfl_down(ssum, off);
    ssum = __shfl(ssum, 0);
    out[o + 258 + j] = e / ssum;
}

// ---------------------------------------------------------------------------
extern "C" void kernel_launch(void* const* d_in, const int* in_sizes, int n_in,
                              void* d_out, int out_size, void* d_ws, size_t ws_size,
                              hipStream_t stream)
{
    const float* values   = (const float*)d_in[0];
    const float* mdp      = (const float*)d_in[1];
    const int*   actions  = (const int*)  d_in[2];
    const int*   a0       = (const int*)  d_in[3];
    const float* h0       = (const float*)d_in[4];
    const float* emb_W    = (const float*)d_in[5];
    const float* emb_b    = (const float*)d_in[6];
    const float* gfw_Wih  = (const float*)d_in[7];
    const float* gfw_Whh  = (const float*)d_in[8];
    const float* gfw_bih  = (const float*)d_in[9];
    const float* gfw_bhh  = (const float*)d_in[10];
    const float* gbw_Wih  = (const float*)d_in[11];
    const float* gbw_Whh  = (const float*)d_in[12];
    const float* gbw_bih  = (const float*)d_in[13];
    const float* gbw_bhh  = (const float*)d_in[14];
    const float* f0_W     = (const float*)d_in[15];
    const float* f0_b     = (const float*)d_in[16];
    const float* f1_W     = (const float*)d_in[17];
    const float* f1_b     = (const float*)d_in[18];
    const float* cell_Wih = (const float*)d_in[19];
    const float* cell_Whh = (const float*)d_in[20];
    const float* cell_bih = (const float*)d_in[21];
    const float* cell_bhh = (const float*)d_in[22];
    const float* critic_W = (const float*)d_in[23];
    const float* critic_b = (const float*)d_in[24];
    const float* qg_W     = (const float*)d_in[25];
    const float* qg_b     = (const float*)d_in[26];
    float* out = (float*)d_out;

    char* base = (char*)d_ws;
    size_t off = 0;
    auto alloc = [&](size_t nf) -> float* {
        float* p = (float*)(base + off);
        off += nf * sizeof(float);
        off = (off + 255) & ~(size_t)255;
        return p;
    };
    float* Mbuf   = alloc(16384ull * 256);   // (n,s,H) line embeddings
    float* Mseq   = alloc(16384ull * 256);   // (s,n,H)
    float* gfA    = alloc(16384ull * 768);   // fw gate inputs (bias folded)
    float* gbA    = alloc(16384ull * 768);   // bw gate inputs (bias folded)
    float* Kbuf   = alloc(256ull * 64 * 512);// K (n, s, 2H)
    float* PKf    = alloc(98304);            // packed Whh frags bf16: 196608 shorts = 384KB
    float* PKb    = alloc(98304);
    float* PKc    = alloc(98304);
    float* hstate = alloc(256ull * 256);
    float* Xc     = alloc(16384ull * 320);
    float* X0c    = alloc(16384ull * 256);
    float* X1c    = alloc(16384ull * 256);
    float* GIc    = alloc(16384ull * 768);
    float* Qc     = alloc(16384ull * 512);
    float* Lc     = alloc(16384ull * 64);
    float* Hallc  = alloc(16384ull * 256);
    float* bias_f = alloc(768);
    float* bias_b = alloc(768);
    float* bias_c = alloc(768);
    (void)ws_size; (void)in_sizes; (void)n_in; (void)out_size;

    dim3 blk(256);

    // Phase 1: embeddings + line-GRU gate inputs + weight prep
    gemm_f32<false, 0><<<dim3(4, 256, 1), blk, 0, stream>>>(
        mdp, 128, 0, emb_W, 256, 0, emb_b, Mbuf, 256, 0, 16384, 256, 128);
    seq_major<<<dim3(16384), blk, 0, stream>>>(Mbuf, Mseq);
    pack_w<<<dim3(96, 3, 1), blk, 0, stream>>>(
        gfw_Whh, gbw_Whh, cell_Whh,
        (unsigned short*)PKf, (unsigned short*)PKb, (unsigned short*)PKc);
    combine_bias<<<dim3(3), blk, 0, stream>>>(gfw_bih, gfw_bhh, gbw_bih, gbw_bhh,
                                              cell_bih, cell_bhh, bias_f, bias_b, bias_c);
    gemm_f32<false, 0><<<dim3(12, 256, 1), blk, 0, stream>>>(
        Mseq, 256, 0, gfw_Wih, 768, 0, bias_f, gfA, 768, 0, 16384, 768, 256);
    gemm_f32<false, 0><<<dim3(12, 256, 1), blk, 0, stream>>>(
        Mseq, 256, 0, gbw_Wih, 768, 0, bias_b, gbA, 768, 0, 16384, 768, 256);
    scan_mfma<1><<<dim3(16, 2, 1), dim3(256), 0, stream>>>(
        gfA, gbA, (const unsigned short*)PKf, (const unsigned short*)PKb,
        nullptr, Kbuf, nullptr, 64);

    // Phase 2/3: chunked x-path GEMMs -> scan -> query/logits/epilogue
    for (int c = 0; c < NCHUNK; c++) {
        int t0 = c * TCHUNK;
        build_x<<<dim3(16384), dim3(320), 0, stream>>>(values, Mbuf, actions, a0, Xc, t0);
        gemm_f32<false, 1><<<dim3(4, 256, 1), blk, 0, stream>>>(
            Xc, 320, 0, f0_W, 256, 0, f0_b, X0c, 256, 0, 16384, 256, 320);
        gemm_f32<false, 1><<<dim3(4, 256, 1), blk, 0, stream>>>(
            X0c, 256, 0, f1_W, 256, 0, f1_b, X1c, 256, 0, 16384, 256, 256);
        gemm_f32<false, 0><<<dim3(12, 256, 1), blk, 0, stream>>>(
            X1c, 256, 0, cell_Wih, 768, 0, bias_c, GIc, 768, 0, 16384, 768, 256);
        scan_mfma<0><<<dim3(16, 1, 1), dim3(256), 0, stream>>>(
            GIc, nullptr, (const unsigned short*)PKc, nullptr,
            (c == 0) ? h0 : (const float*)hstate, Hallc, hstate, TCHUNK);
        gemm_f32<false, 0><<<dim3(8, 256, 1), blk, 0, stream>>>(
            Hallc, 256, 0, qg_W, 512, 0, qg_b, Qc, 512, 0, 16384, 512, 256);
        gemm_f32<true, 0><<<dim3(1, 1, 256), blk, 0, stream>>>(
            Qc, 131072, 512, Kbuf, 512, 32768, nullptr, Lc, 16384, 64, 64, 64, 512);
        epilogue_k<<<dim3(16384), dim3(64), 0, stream>>>(
            Hallc, Lc, actions, critic_W, critic_b, out, t0);
    }
}

// Round 6
// 2502.491 us; speedup vs baseline: 2.0980x; 2.0980x over previous
//
#include <hip/hip_runtime.h>

// Problem constants (reference: T=512, N=256, H=256, HR=64, WC=128, V=64)
#define TSTEPS 512
#define NBATCH 256
#define HID    256
#define TCHUNK 64
#define NCHUNK 8

typedef __attribute__((ext_vector_type(8))) short bf16x8;
typedef __attribute__((ext_vector_type(4))) float f32x4;

__device__ __forceinline__ unsigned short f2b(float x) {
    union { float f; unsigned int u; } c; c.f = x;
    unsigned int u = c.u;
    return (unsigned short)((u + 0x7fffu + ((u >> 16) & 1u)) >> 16);
}

__device__ __forceinline__ void gload_lds16(const float* g, float* l) {
    __builtin_amdgcn_global_load_lds(
        (const __attribute__((address_space(1))) unsigned int*)g,
        (__attribute__((address_space(3))) unsigned int*)l,
        16, 0, 0);
}

// ---------------------------------------------------------------------------
// Generic GEMM (256 thr): C = act(A@B + bias). Used for prologue + logits +
// tail qg. (unchanged — verified correct)
// ---------------------------------------------------------------------------
template<bool TRANS_B, int ACT>
__global__ __launch_bounds__(256) void gemm_f32(
    const float* __restrict__ A, long lda, long sA,
    const float* __restrict__ B, long ldb, long sB,
    const float* __restrict__ bias,
    float* __restrict__ C, long ldc, long sC,
    int M, int N, int K)
{
    __shared__ __align__(16) unsigned short As[64][32];
    __shared__ __align__(16) unsigned short Bs[64][32];
    const int z = blockIdx.z;
    A += (long)z * sA; B += (long)z * sB; C += (long)z * sC;
    const int n0 = blockIdx.x * 64, m0 = blockIdx.y * 64;
    const int tid  = threadIdx.x;
    const int lane = tid & 63, w = tid >> 6;
    const int wr = (w >> 1) * 32, wc = (w & 1) * 32;

    f32x4 acc[2][2];
#pragma unroll
    for (int i = 0; i < 2; i++)
#pragma unroll
        for (int j = 0; j < 2; j++) acc[i][j] = (f32x4){0.f, 0.f, 0.f, 0.f};

    for (int k0 = 0; k0 < K; k0 += 32) {
        {
            const int r = tid >> 2, ck = (tid & 3) << 3;
            const float* s = A + (long)(m0 + r) * lda + k0 + ck;
            float4 v0 = *(const float4*)s, v1 = *(const float4*)(s + 4);
            unsigned short* d = &As[r][ck];
            d[0] = f2b(v0.x); d[1] = f2b(v0.y); d[2] = f2b(v0.z); d[3] = f2b(v0.w);
            d[4] = f2b(v1.x); d[5] = f2b(v1.y); d[6] = f2b(v1.z); d[7] = f2b(v1.w);
        }
        if (TRANS_B) {
            const int r = tid >> 2, ck = (tid & 3) << 3;
            const float* s = B + (long)(n0 + r) * ldb + k0 + ck;
            float4 v0 = *(const float4*)s, v1 = *(const float4*)(s + 4);
            unsigned short* d = &Bs[r][ck];
            d[0] = f2b(v0.x); d[1] = f2b(v0.y); d[2] = f2b(v0.z); d[3] = f2b(v0.w);
            d[4] = f2b(v1.x); d[5] = f2b(v1.y); d[6] = f2b(v1.z); d[7] = f2b(v1.w);
        } else {
            const int kk = tid >> 3, cn = (tid & 7) << 3;
            const float* s = B + (long)(k0 + kk) * ldb + n0 + cn;
            float4 v0 = *(const float4*)s, v1 = *(const float4*)(s + 4);
            Bs[cn + 0][kk] = f2b(v0.x); Bs[cn + 1][kk] = f2b(v0.y);
            Bs[cn + 2][kk] = f2b(v0.z); Bs[cn + 3][kk] = f2b(v0.w);
            Bs[cn + 4][kk] = f2b(v1.x); Bs[cn + 5][kk] = f2b(v1.y);
            Bs[cn + 6][kk] = f2b(v1.z); Bs[cn + 7][kk] = f2b(v1.w);
        }
        __syncthreads();
        const int q8 = (lane >> 4) << 3;
        bf16x8 a0 = *(const bf16x8*)&As[wr +      (lane & 15)][q8];
        bf16x8 a1 = *(const bf16x8*)&As[wr + 16 + (lane & 15)][q8];
        bf16x8 b0 = *(const bf16x8*)&Bs[wc +      (lane & 15)][q8];
        bf16x8 b1 = *(const bf16x8*)&Bs[wc + 16 + (lane & 15)][q8];
        acc[0][0] = __builtin_amdgcn_mfma_f32_16x16x32_bf16(a0, b0, acc[0][0], 0, 0, 0);
        acc[0][1] = __builtin_amdgcn_mfma_f32_16x16x32_bf16(a0, b1, acc[0][1], 0, 0, 0);
        acc[1][0] = __builtin_amdgcn_mfma_f32_16x16x32_bf16(a1, b0, acc[1][0], 0, 0, 0);
        acc[1][1] = __builtin_amdgcn_mfma_f32_16x16x32_bf16(a1, b1, acc[1][1], 0, 0, 0);
        __syncthreads();
    }
    const int cq = lane >> 4, cc = lane & 15;
#pragma unroll
    for (int i = 0; i < 2; i++)
#pragma unroll
        for (int j = 0; j < 2; j++) {
#pragma unroll
            for (int rg = 0; rg < 4; rg++) {
                int row = m0 + wr + i * 16 + cq * 4 + rg;
                int col = n0 + wc + j * 16 + cc;
                float v = acc[i][j][rg];
                if (bias) v += bias[col];
                if (ACT == 1) v = v > 0.f ? v : 0.f;
                C[(long)row * ldc + col] = v;
            }
        }
}

// ---------------------------------------------------------------------------
// Helpers (unchanged)
// ---------------------------------------------------------------------------
__global__ void combine_bias(const float* a0, const float* b0,
                             const float* a1, const float* b1,
                             const float* a2, const float* b2,
                             float* o0, float* o1, float* o2)
{
    int i = blockIdx.x * 256 + threadIdx.x;
    o0[i] = a0[i] + b0[i];
    o1[i] = a1[i] + b1[i];
    o2[i] = a2[i] + b2[i];
}

__global__ void seq_major(const float* __restrict__ M, float* __restrict__ Mseq)
{
    int b = blockIdx.x;
    int s = b >> 8, n = b & 255;
    int t = threadIdx.x;
    Mseq[(long)b * 256 + t] = M[((long)n * 64 + s) * 256 + t];
}

// ---------------------------------------------------------------------------
// pack_w: V3 (8-wave) fragment layout.
//   chunk = ((w*6 + f)*8 + kt)*64 + lane,  f = g*2+hh (g<3, hh<2), w<8
//   PK[chunk][j] = bf16( Whh[(kt*32 + q*8 + j)*768 + g*256 + w*32 + hh*16 + c] )
// ---------------------------------------------------------------------------
__global__ __launch_bounds__(256) void pack_w(
    const float* __restrict__ Wf, const float* __restrict__ Wb, const float* __restrict__ Wc,
    unsigned short* __restrict__ Pf, unsigned short* __restrict__ Pb, unsigned short* __restrict__ Pc)
{
    int chunk = blockIdx.x * 256 + threadIdx.x;      // 0..24575
    const float* W = (blockIdx.y == 0) ? Wf : ((blockIdx.y == 1) ? Wb : Wc);
    unsigned short* P = (blockIdx.y == 0) ? Pf : ((blockIdx.y == 1) ? Pb : Pc);
    int lane = chunk & 63;
    int kt   = (chunk >> 6) & 7;
    int f    = (chunk >> 9) % 6;
    int w    = chunk / 3072;
    int g = f >> 1, hh = f & 1;
    int c = lane & 15, q = lane >> 4;
    int col = g * 256 + w * 32 + hh * 16 + c;
    int k0  = kt * 32 + q * 8;
    unsigned int v[8];
#pragma unroll
    for (int j = 0; j < 8; j++) v[j] = f2b(W[(long)(k0 + j) * 768 + col]);
    uint4 o;
    o.x = v[0] | (v[1] << 16); o.y = v[2] | (v[3] << 16);
    o.z = v[4] | (v[5] << 16); o.w = v[6] | (v[7] << 16);
    *(uint4*)&P[(long)chunk * 8] = o;
}

__global__ void build_x(const float* __restrict__ values, const float* __restrict__ Mbuf,
                        const int* __restrict__ actions, const int* __restrict__ a0,
                        float* __restrict__ Xc, int t0)
{
    int m = blockIdx.x;
    int tl = m >> 8, n = m & 255;
    int t = t0 + tl;
    int c = threadIdx.x;
    float v;
    if (c < 64) {
        v = values[((long)t * 256 + n) * 64 + c];
    } else {
        int ap = (t == 0) ? a0[n] : actions[(long)(t - 1) * 256 + n];
        v = Mbuf[((long)n * 64 + ap) * 256 + (c - 64)];
    }
    Xc[(long)m * 320 + c] = v;
}

// ---------------------------------------------------------------------------
// Fused kernel: block-role multiplexing so the 240 CUs idle during the
// 16-block serial scan do the x-path / KGRU / qg work of other chunks.
// Roles share NO barriers (workgroup scope) and write slot-disjoint ring
// buffers. LDS is a union (scan 115.7KB dominates -> 1 block/CU, 8 waves,
// 2 waves/SIMD — identical occupancy to the proven v3 scan).
// ---------------------------------------------------------------------------
struct GemmRole {
    const float* A; const float* B; const float* bias; float* C;
    int K; long lda; long ldb; long ldc; int act; int nblocks; int ntn;
};

union FusedLds {
    struct { unsigned short hbuf[2][16][264]; float gibuf[2][16 * 772]; } s;
    struct { unsigned short As[64][32]; unsigned short Bs[128][32]; } g;
};

// ---- scan role: EXACT v3 structure (8 waves, split-hh, fences, vmcnt(8)),
// with hoisted out-pointers; runtime kgru/d flags. ----
__device__ __forceinline__ void scan_role(FusedLds* L,
    const float* gi, const unsigned short* PK, const float* h_init,
    float* outp, float* h_state, int n0, int steps, int kgru, int d)
{
    auto& hbuf  = L->s.hbuf;
    auto& gibuf = L->s.gibuf;
    const int tid = threadIdx.x;
    const int w = tid >> 6, lane = tid & 63;
    const int q = lane >> 4, c = lane & 15, q8 = q << 3;
    const int wcol = w * 32;

    bf16x8 Bf[6][8];
#pragma unroll
    for (int f = 0; f < 6; f++)
#pragma unroll
        for (int kt = 0; kt < 8; kt++)
            Bf[f][kt] = *(const bf16x8*)&PK[(((long)(w * 6 + f) * 8 + kt) * 64 + lane) * 8];

    f32x4 hreg[2];
#pragma unroll
    for (int hh = 0; hh < 2; hh++)
#pragma unroll
        for (int rg = 0; rg < 4; rg++) {
            float v = 0.f;
            if (!kgru) v = h_init[(long)(n0 + q * 4 + rg) * 256 + wcol + hh * 16 + c];
            hreg[hh][rg] = v;
            hbuf[1][q * 4 + rg][wcol + hh * 16 + c] = f2b(v);
        }

    const int row0 = kgru ? (d ? 63 : 0) : 0;
    const long gstride = (kgru && d) ? -196608L : 196608L;
    const float* gsrc = gi + ((long)row0 * 256 + n0) * 768;
    float* optr[4];
    long ostride;
    if (kgru) {
        ostride = d ? -512L : 512L;
#pragma unroll
        for (int rg = 0; rg < 4; rg++)
            optr[rg] = outp + ((long)(n0 + q * 4 + rg) * 64 + row0) * 512 + d * 256 + wcol + c;
    } else {
        ostride = 65536L;
#pragma unroll
        for (int rg = 0; rg < 4; rg++)
            optr[rg] = outp + (long)(n0 + q * 4 + rg) * 256 + wcol + c;
    }

#pragma unroll
    for (int i = 0; i < 6; i++) {
        int idx = w * 6 + i;
        int r = idx / 3, ch = idx % 3;
        gload_lds16(gsrc + (long)r * 768 + ch * 256 + lane * 4,
                    &gibuf[0][r * 772 + ch * 256]);
    }
    __syncthreads();

    for (int s = 0; s < steps; s++) {
        const int cur = s & 1;
        if (s + 1 < steps) {
            const float* src = gsrc + gstride;
#pragma unroll
            for (int i = 0; i < 6; i++) {
                int idx = w * 6 + i;
                int r = idx / 3, ch = idx % 3;
                gload_lds16(src + (long)r * 768 + ch * 256 + lane * 4,
                            &gibuf[cur ^ 1][r * 772 + ch * 256]);
            }
        }
        gsrc += gstride;
        asm volatile("" ::: "memory");

        const unsigned short* hrd = &hbuf[cur ^ 1][0][0];
        const float* gp = &gibuf[cur][(q * 4) * 772 + wcol + c];
        unsigned short* hwr = &hbuf[cur][q * 4][wcol + c];

#pragma unroll
        for (int hh = 0; hh < 2; hh++) {
            f32x4 ar = (f32x4){0.f, 0.f, 0.f, 0.f};
            f32x4 az = (f32x4){0.f, 0.f, 0.f, 0.f};
            f32x4 an = (f32x4){0.f, 0.f, 0.f, 0.f};
#pragma unroll
            for (int kt = 0; kt < 8; kt++) {
                bf16x8 a = *(const bf16x8*)&hrd[c * 264 + kt * 32 + q8];
                ar = __builtin_amdgcn_mfma_f32_16x16x32_bf16(a, Bf[0 + hh][kt], ar, 0, 0, 0);
                az = __builtin_amdgcn_mfma_f32_16x16x32_bf16(a, Bf[2 + hh][kt], az, 0, 0, 0);
                an = __builtin_amdgcn_mfma_f32_16x16x32_bf16(a, Bf[4 + hh][kt], an, 0, 0, 0);
            }
#pragma unroll
            for (int rg = 0; rg < 4; rg++) {
                float gr = gp[rg * 772 +       hh * 16];
                float gz = gp[rg * 772 + 256 + hh * 16];
                float gn = gp[rg * 772 + 512 + hh * 16];
                float r  = __builtin_amdgcn_rcpf(1.f + __expf(-(gr + ar[rg])));
                float zg = __builtin_amdgcn_rcpf(1.f + __expf(-(gz + az[rg])));
                float nn = 1.f - 2.f * __builtin_amdgcn_rcpf(1.f + __expf(2.f * (gn + r * an[rg])));
                float hv = (1.f - zg) * nn + zg * hreg[hh][rg];
                hreg[hh][rg] = hv;
                hwr[rg * 264 + hh * 16] = f2b(hv);
                optr[rg][hh * 16] = hv;
            }
            asm volatile("" ::: "memory");
        }

#pragma unroll
        for (int rg = 0; rg < 4; rg++) optr[rg] += ostride;

        asm volatile("s_waitcnt vmcnt(8) lgkmcnt(0)" ::: "memory");
        __builtin_amdgcn_sched_barrier(0);
        __builtin_amdgcn_s_barrier();
        __builtin_amdgcn_sched_barrier(0);
    }

    if (!kgru) {
#pragma unroll
        for (int hh = 0; hh < 2; hh++)
#pragma unroll
            for (int rg = 0; rg < 4; rg++)
                h_state[(long)(n0 + q * 4 + rg) * 256 + wcol + hh * 16 + c] = hreg[hh][rg];
    }
}

// ---- gemm role: 512-thread 64x128 tile, B stored (K,N), fp32 in/out ----
__device__ __forceinline__ void gemm_role(FusedLds* L, const GemmRole& R, int rb)
{
    auto& As = L->g.As;
    auto& Bs = L->g.Bs;
    const int tid = threadIdx.x;
    const int lane = tid & 63, w = tid >> 6;
    const int q8 = (lane >> 4) << 3;
    const int mt = rb / R.ntn, nt = rb % R.ntn;
    const long m0 = (long)mt * 64, n0 = (long)nt * 128;
    const int wr = (w >> 2) * 32, wc = (w & 3) * 32;

    f32x4 acc[2][2];
#pragma unroll
    for (int i = 0; i < 2; i++)
#pragma unroll
        for (int j = 0; j < 2; j++) acc[i][j] = (f32x4){0.f, 0.f, 0.f, 0.f};

    for (int k0 = 0; k0 < R.K; k0 += 32) {
        {   // A: 64 x 32, 512 thr x 4 floats
            const int r = tid >> 3, ck = (tid & 7) << 2;
            const float* s = R.A + (m0 + r) * R.lda + k0 + ck;
            float4 v = *(const float4*)s;
            unsigned short* dp = &As[r][ck];
            dp[0] = f2b(v.x); dp[1] = f2b(v.y); dp[2] = f2b(v.z); dp[3] = f2b(v.w);
        }
        {   // B: 32 x 128 scatter-transpose, 512 thr x 8 floats
            const int kk = tid >> 4, cn = (tid & 15) << 3;
            const float* s = R.B + (long)(k0 + kk) * R.ldb + n0 + cn;
            float4 v0 = *(const float4*)s, v1 = *(const float4*)(s + 4);
            Bs[cn + 0][kk] = f2b(v0.x); Bs[cn + 1][kk] = f2b(v0.y);
            Bs[cn + 2][kk] = f2b(v0.z); Bs[cn + 3][kk] = f2b(v0.w);
            Bs[cn + 4][kk] = f2b(v1.x); Bs[cn + 5][kk] = f2b(v1.y);
            Bs[cn + 6][kk] = f2b(v1.z); Bs[cn + 7][kk] = f2b(v1.w);
        }
        __syncthreads();
        bf16x8 a0 = *(const bf16x8*)&As[wr +      (lane & 15)][q8];
        bf16x8 a1 = *(const bf16x8*)&As[wr + 16 + (lane & 15)][q8];
        bf16x8 b0 = *(const bf16x8*)&Bs[wc +      (lane & 15)][q8];
        bf16x8 b1 = *(const bf16x8*)&Bs[wc + 16 + (lane & 15)][q8];
        acc[0][0] = __builtin_amdgcn_mfma_f32_16x16x32_bf16(a0, b0, acc[0][0], 0, 0, 0);
        acc[0][1] = __builtin_amdgcn_mfma_f32_16x16x32_bf16(a0, b1, acc[0][1], 0, 0, 0);
        acc[1][0] = __builtin_amdgcn_mfma_f32_16x16x32_bf16(a1, b0, acc[1][0], 0, 0, 0);
        acc[1][1] = __builtin_amdgcn_mfma_f32_16x16x32_bf16(a1, b1, acc[1][1], 0, 0, 0);
        __syncthreads();
    }
    const int cq = lane >> 4, cc = lane & 15;
#pragma unroll
    for (int i = 0; i < 2; i++)
#pragma unroll
        for (int j = 0; j < 2; j++) {
#pragma unroll
            for (int rg = 0; rg < 4; rg++) {
                long row = m0 + wr + i * 16 + cq * 4 + rg;
                long col = n0 + wc + j * 16 + cc;
                float v = acc[i][j][rg];
                if (R.bias) v += R.bias[col];
                if (R.act == 1) v = v > 0.f ? v : 0.f;
                R.C[row * R.ldc + col] = v;
            }
        }
}

// ---- build_x role: 128 blocks x 128 rows; threads 0..319 = cols ----
__device__ __forceinline__ void bx_role(int rb,
    const float* values, const float* Mbuf, const int* actions, const int* a0,
    float* Xd, int t0)
{
    const int tid = threadIdx.x;
    if (tid >= 320) return;      // no barriers in this role — safe
    for (int rr = 0; rr < 128; rr++) {
        int m = rb * 128 + rr;
        int tl = m >> 8, n = m & 255;
        int t = t0 + tl;
        float v;
        if (tid < 64) {
            v = values[((long)t * 256 + n) * 64 + tid];
        } else {
            int ap = (t == 0) ? a0[n] : actions[(long)(t - 1) * 256 + n];
            v = Mbuf[((long)n * 64 + ap) * 256 + (tid - 64)];
        }
        Xd[(long)m * 320 + tid] = v;
    }
}

__global__ __launch_bounds__(512, 2) void fused_k(
    const float* sc_gi, const unsigned short* sc_PK, const float* sc_hinit,
    float* sc_out, float* sc_hstate,
    int kgru_nblk, const float* kg_gi0, const float* kg_gi1,
    const unsigned short* kg_PK0, const unsigned short* kg_PK1, float* kg_out,
    GemmRole g0, GemmRole g1, GemmRole g2, GemmRole g3,
    int bx_nblk, const float* values, const float* Mbuf,
    const int* actions, const int* a0, float* bx_dst, int bx_t0)
{
    __shared__ __align__(16) FusedLds L;
    int b = blockIdx.x;
    if (b < 16) {
        scan_role(&L, sc_gi, sc_PK, sc_hinit, sc_out, sc_hstate, b * 16, TCHUNK, 0, 0);
        return;
    }
    b -= 16;
    if (b < kgru_nblk) {
        int d = b >> 4, n0 = (b & 15) * 16;
        scan_role(&L, d ? kg_gi1 : kg_gi0, d ? kg_PK1 : kg_PK0, nullptr,
                  kg_out, nullptr, n0, 64, 1, d);
        return;
    }
    b -= kgru_nblk;
    if (b < g0.nblocks) { gemm_role(&L, g0, b); return; }
    b -= g0.nblocks;
    if (b < g1.nblocks) { gemm_role(&L, g1, b); return; }
    b -= g1.nblocks;
    if (b < g2.nblocks) { gemm_role(&L, g2, b); return; }
    b -= g2.nblocks;
    if (b < g3.nblocks) { gemm_role(&L, g3, b); return; }
    b -= g3.nblocks;
    if (b < bx_nblk) bx_role(b, values, Mbuf, actions, a0, bx_dst, bx_t0);
}

// ---------------------------------------------------------------------------
// Epilogue (unchanged)
// ---------------------------------------------------------------------------
__global__ __launch_bounds__(64) void epilogue_k(
    const float* __restrict__ Hallc, const float* __restrict__ Lc,
    const int* __restrict__ actions,
    const float* __restrict__ critic_W, const float* __restrict__ critic_b,
    float* __restrict__ out, int t0)
{
    int m = blockIdx.x;
    int tl = m >> 8, n = m & 255;
    int t = t0 + tl;
    int j = threadIdx.x;
    long o = ((long)t * 256 + n) * 322;
    const float* h = Hallc + (long)m * 256;
    float part = 0.f;
#pragma unroll
    for (int i = 0; i < 4; i++) {
        float hv = h[j + 64 * i];
        out[o + 2 + j + 64 * i] = hv;
        part += hv * critic_W[j + 64 * i];
    }
    for (int off = 32; off > 0; off >>= 1) part += __shfl_down(part, off);
    if (j == 0) {
        out[o]     = (float)actions[(long)t * 256 + n];
        out[o + 1] = part + critic_b[0];
    }
    float x = Lc[(long)m * 64 + j];
    float mx = x;
    for (int off = 32; off > 0; off >>= 1) mx = fmaxf(mx, __shfl_down(mx, off));
    mx = __shfl(mx, 0);
    float e = __expf(x - mx);
    float ssum = e;
    for (int off = 32; off > 0; off >>= 1) ssum += __shfl_down(ssum, off);
    ssum = __shfl(ssum, 0);
    out[o + 258 + j] = e / ssum;
}

// ---------------------------------------------------------------------------
extern "C" void kernel_launch(void* const* d_in, const int* in_sizes, int n_in,
                              void* d_out, int out_size, void* d_ws, size_t ws_size,
                              hipStream_t stream)
{
    const float* values   = (const float*)d_in[0];
    const float* mdp      = (const float*)d_in[1];
    const int*   actions  = (const int*)  d_in[2];
    const int*   a0       = (const int*)  d_in[3];
    const float* h0       = (const float*)d_in[4];
    const float* emb_W    = (const float*)d_in[5];
    const float* emb_b    = (const float*)d_in[6];
    const float* gfw_Wih  = (const float*)d_in[7];
    const float* gfw_Whh  = (const float*)d_in[8];
    const float* gfw_bih  = (const float*)d_in[9];
    const float* gfw_bhh  = (const float*)d_in[10];
    const float* gbw_Wih  = (const float*)d_in[11];
    const float* gbw_Whh  = (const float*)d_in[12];
    const float* gbw_bih  = (const float*)d_in[13];
    const float* gbw_bhh  = (const float*)d_in[14];
    const float* f0_W     = (const float*)d_in[15];
    const float* f0_b     = (const float*)d_in[16];
    const float* f1_W     = (const float*)d_in[17];
    const float* f1_b     = (const float*)d_in[18];
    const float* cell_Wih = (const float*)d_in[19];
    const float* cell_Whh = (const float*)d_in[20];
    const float* cell_bih = (const float*)d_in[21];
    const float* cell_bhh = (const float*)d_in[22];
    const float* critic_W = (const float*)d_in[23];
    const float* critic_b = (const float*)d_in[24];
    const float* qg_W     = (const float*)d_in[25];
    const float* qg_b     = (const float*)d_in[26];
    float* out = (float*)d_out;

    char* base = (char*)d_ws;
    size_t off = 0;
    auto alloc = [&](size_t nf) -> float* {
        float* p = (float*)(base + off);
        off += nf * sizeof(float);
        off = (off + 255) & ~(size_t)255;
        return p;
    };
    float* Mbuf   = alloc(16384ull * 256);
    float* Mseq   = alloc(16384ull * 256);
    float* gfA    = alloc(16384ull * 768);
    float* gbA    = alloc(16384ull * 768);
    float* Kbuf   = alloc(256ull * 64 * 512);
    float* PKf    = alloc(98304);
    float* PKb    = alloc(98304);
    float* PKc    = alloc(98304);
    float* hstate = alloc(256ull * 256);
    float* Xr[2]    = { alloc(16384ull * 320), alloc(16384ull * 320) };
    float* X0r[2]   = { alloc(16384ull * 256), alloc(16384ull * 256) };
    float* X1r[2]   = { alloc(16384ull * 256), alloc(16384ull * 256) };
    float* GIr[2]   = { alloc(16384ull * 768), alloc(16384ull * 768) };
    float* Hallr[2] = { alloc(16384ull * 256), alloc(16384ull * 256) };
    float* Q      = alloc(16384ull * 512);
    float* Lc     = alloc(16384ull * 64);
    float* bias_f = alloc(768);
    float* bias_b = alloc(768);
    float* bias_c = alloc(768);
    (void)ws_size; (void)in_sizes; (void)n_in; (void)out_size;

    dim3 blk(256);

    // ---- Phase 1: embeddings, gate-input GEMMs, weight packing ----
    gemm_f32<false, 0><<<dim3(4, 256, 1), blk, 0, stream>>>(
        mdp, 128, 0, emb_W, 256, 0, emb_b, Mbuf, 256, 0, 16384, 256, 128);
    seq_major<<<dim3(16384), blk, 0, stream>>>(Mbuf, Mseq);
    pack_w<<<dim3(96, 3, 1), blk, 0, stream>>>(
        gfw_Whh, gbw_Whh, cell_Whh,
        (unsigned short*)PKf, (unsigned short*)PKb, (unsigned short*)PKc);
    combine_bias<<<dim3(3), blk, 0, stream>>>(gfw_bih, gfw_bhh, gbw_bih, gbw_bhh,
                                              cell_bih, cell_bhh, bias_f, bias_b, bias_c);
    gemm_f32<false, 0><<<dim3(12, 256, 1), blk, 0, stream>>>(
        Mseq, 256, 0, gfw_Wih, 768, 0, bias_f, gfA, 768, 0, 16384, 768, 256);
    gemm_f32<false, 0><<<dim3(12, 256, 1), blk, 0, stream>>>(
        Mseq, 256, 0, gbw_Wih, 768, 0, bias_b, gbA, 768, 0, 16384, 768, 256);

    // ---- Pipeline priming (x-path for chunks 0..3 partial) ----
    build_x<<<dim3(16384), dim3(320), 0, stream>>>(values, Mbuf, actions, a0, Xr[0], 0);
    gemm_f32<false, 1><<<dim3(4, 256, 1), blk, 0, stream>>>(
        Xr[0], 320, 0, f0_W, 256, 0, f0_b, X0r[0], 256, 0, 16384, 256, 320);
    build_x<<<dim3(16384), dim3(320), 0, stream>>>(values, Mbuf, actions, a0, Xr[1], 64);
    gemm_f32<false, 1><<<dim3(4, 256, 1), blk, 0, stream>>>(
        Xr[1], 320, 0, f0_W, 256, 0, f0_b, X0r[1], 256, 0, 16384, 256, 320);
    gemm_f32<false, 1><<<dim3(4, 256, 1), blk, 0, stream>>>(
        X0r[0], 256, 0, f1_W, 256, 0, f1_b, X1r[0], 256, 0, 16384, 256, 256);
    build_x<<<dim3(16384), dim3(320), 0, stream>>>(values, Mbuf, actions, a0, Xr[0], 128);
    gemm_f32<false, 1><<<dim3(4, 256, 1), blk, 0, stream>>>(
        Xr[0], 320, 0, f0_W, 256, 0, f0_b, X0r[0], 256, 0, 16384, 256, 320);
    gemm_f32<false, 1><<<dim3(4, 256, 1), blk, 0, stream>>>(
        X0r[1], 256, 0, f1_W, 256, 0, f1_b, X1r[1], 256, 0, 16384, 256, 256);
    build_x<<<dim3(16384), dim3(320), 0, stream>>>(values, Mbuf, actions, a0, Xr[1], 192);
    gemm_f32<false, 0><<<dim3(12, 256, 1), blk, 0, stream>>>(
        X1r[0], 256, 0, cell_Wih, 768, 0, bias_c, GIr[0], 768, 0, 16384, 768, 256);

    // ---- Fused pipeline: per chunk c, one kernel runs
    //   scan(c) [16 blk] + kgru(c==0) [32] + f0(c+3) + f1(c+2) + GI(c+1)
    //   + qg(c-1) + build_x(c+4); then serial logits/epilogue for c-1. ----
    for (int c = 0; c < NCHUNK; c++) {
        GemmRole g0{}, g1{}, g2{}, g3{};
        if (c <= 4) g0 = GemmRole{ Xr[(c + 1) & 1], f0_W, f0_b, X0r[(c + 1) & 1],
                                   320, 320, 256, 256, 1, 512, 2 };
        if (c <= 5) g1 = GemmRole{ X0r[c & 1], f1_W, f1_b, X1r[c & 1],
                                   256, 256, 256, 256, 1, 512, 2 };
        if (c <= 6) g2 = GemmRole{ X1r[(c + 1) & 1], cell_Wih, bias_c, GIr[(c + 1) & 1],
                                   256, 256, 768, 768, 0, 1536, 6 };
        if (c >= 1) g3 = GemmRole{ Hallr[(c + 1) & 1], qg_W, qg_b, Q,
                                   256, 256, 512, 512, 0, 1024, 4 };
        int kgn = (c == 0) ? 32 : 0;
        int bxn = (c <= 3) ? 128 : 0;
        int total = 16 + kgn + g0.nblocks + g1.nblocks + g2.nblocks + g3.nblocks + bxn;

        fused_k<<<dim3(total), dim3(512), 0, stream>>>(
            GIr[c & 1], (const unsigned short*)PKc, (c == 0) ? h0 : (const float*)hstate,
            Hallr[c & 1], hstate,
            kgn, gfA, gbA, (const unsigned short*)PKf, (const unsigned short*)PKb, Kbuf,
            g0, g1, g2, g3,
            bxn, values, Mbuf, actions, a0, Xr[c & 1], (c + 4) * 64);

        if (c >= 1) {
            gemm_f32<true, 0><<<dim3(1, 1, 256), blk, 0, stream>>>(
                Q, 131072, 512, Kbuf, 512, 32768, nullptr, Lc, 16384, 64, 64, 64, 512);
            epilogue_k<<<dim3(16384), dim3(64), 0, stream>>>(
                Hallr[(c + 1) & 1], Lc, actions, critic_W, critic_b, out, (c - 1) * 64);
        }
    }

    // ---- Tail: chunk 7 qg/logits/epilogue ----
    gemm_f32<false, 0><<<dim3(8, 256, 1), blk, 0, stream>>>(
        Hallr[1], 256, 0, qg_W, 512, 0, qg_b, Q, 512, 0, 16384, 512, 256);
    gemm_f32<true, 0><<<dim3(1, 1, 256), blk, 0, stream>>>(
        Q, 131072, 512, Kbuf, 512, 32768, nullptr, Lc, 16384, 64, 64, 64, 512);
    epilogue_k<<<dim3(16384), dim3(64), 0, stream>>>(
        Hallr[1], Lc, actions, critic_W, critic_b, out, 448);
}

// Round 7
// 2123.439 us; speedup vs baseline: 2.4725x; 1.1785x over previous
//
#include <hip/hip_runtime.h>

// Problem constants (reference: T=512, N=256, H=256, HR=64, WC=128, V=64)
#define TSTEPS 512
#define NBATCH 256
#define HID    256
#define TCHUNK 64
#define NCHUNK 8

typedef __attribute__((ext_vector_type(8))) short bf16x8;
typedef __attribute__((ext_vector_type(4))) float f32x4;

__device__ __forceinline__ unsigned short f2b(float x) {
    union { float f; unsigned int u; } c; c.f = x;
    unsigned int u = c.u;
    return (unsigned short)((u + 0x7fffu + ((u >> 16) & 1u)) >> 16);
}

__device__ __forceinline__ void gload_lds16(const float* g, float* l) {
    __builtin_amdgcn_global_load_lds(
        (const __attribute__((address_space(1))) unsigned int*)g,
        (__attribute__((address_space(3))) unsigned int*)l,
        16, 0, 0);
}

// LDS bank-conflict fix: XOR-swizzle the 16B granule index of a [row][32]
// bf16 tile with (row>>3)&3. Reads: 64 lanes -> 8 classes x 8 lanes = 2
// lanes/bank (free, m136). Scatter writes (rows 8 apart): 16-way -> 4-way.
__device__ __forceinline__ int swzi(int row, int g) {
    return ((g ^ ((row >> 3) & 3)) << 3);
}

// ---------------------------------------------------------------------------
// Generic GEMM (256 thr): C = act(A@B + bias). Prologue + tail. Swizzled LDS.
// ---------------------------------------------------------------------------
template<bool TRANS_B, int ACT>
__global__ __launch_bounds__(256) void gemm_f32(
    const float* __restrict__ A, long lda, long sA,
    const float* __restrict__ B, long ldb, long sB,
    const float* __restrict__ bias,
    float* __restrict__ C, long ldc, long sC,
    int M, int N, int K)
{
    __shared__ __align__(16) unsigned short As[64][32];
    __shared__ __align__(16) unsigned short Bs[64][32];
    const int z = blockIdx.z;
    A += (long)z * sA; B += (long)z * sB; C += (long)z * sC;
    const int n0 = blockIdx.x * 64, m0 = blockIdx.y * 64;
    const int tid  = threadIdx.x;
    const int lane = tid & 63, w = tid >> 6;
    const int wr = (w >> 1) * 32, wc = (w & 1) * 32;

    f32x4 acc[2][2];
#pragma unroll
    for (int i = 0; i < 2; i++)
#pragma unroll
        for (int j = 0; j < 2; j++) acc[i][j] = (f32x4){0.f, 0.f, 0.f, 0.f};

    for (int k0 = 0; k0 < K; k0 += 32) {
        {
            const int r = tid >> 2, ck = (tid & 3) << 3;
            const float* s = A + (long)(m0 + r) * lda + k0 + ck;
            float4 v0 = *(const float4*)s, v1 = *(const float4*)(s + 4);
            unsigned short* d = &As[r][swzi(r, ck >> 3)];
            d[0] = f2b(v0.x); d[1] = f2b(v0.y); d[2] = f2b(v0.z); d[3] = f2b(v0.w);
            d[4] = f2b(v1.x); d[5] = f2b(v1.y); d[6] = f2b(v1.z); d[7] = f2b(v1.w);
        }
        if (TRANS_B) {
            const int r = tid >> 2, ck = (tid & 3) << 3;
            const float* s = B + (long)(n0 + r) * ldb + k0 + ck;
            float4 v0 = *(const float4*)s, v1 = *(const float4*)(s + 4);
            unsigned short* d = &Bs[r][swzi(r, ck >> 3)];
            d[0] = f2b(v0.x); d[1] = f2b(v0.y); d[2] = f2b(v0.z); d[3] = f2b(v0.w);
            d[4] = f2b(v1.x); d[5] = f2b(v1.y); d[6] = f2b(v1.z); d[7] = f2b(v1.w);
        } else {
            const int kk = tid >> 3, cn = (tid & 7) << 3;
            const float* s = B + (long)(k0 + kk) * ldb + n0 + cn;
            float4 v0 = *(const float4*)s, v1 = *(const float4*)(s + 4);
            const int sc = swzi(cn, kk >> 3) + (kk & 7);   // rows cn..cn+7 share row>>3
            Bs[cn + 0][sc] = f2b(v0.x); Bs[cn + 1][sc] = f2b(v0.y);
            Bs[cn + 2][sc] = f2b(v0.z); Bs[cn + 3][sc] = f2b(v0.w);
            Bs[cn + 4][sc] = f2b(v1.x); Bs[cn + 5][sc] = f2b(v1.y);
            Bs[cn + 6][sc] = f2b(v1.z); Bs[cn + 7][sc] = f2b(v1.w);
        }
        __syncthreads();
        const int l15 = lane & 15, q = lane >> 4;
        bf16x8 a0 = *(const bf16x8*)&As[wr +      l15][swzi(wr +      l15, q)];
        bf16x8 a1 = *(const bf16x8*)&As[wr + 16 + l15][swzi(wr + 16 + l15, q)];
        bf16x8 b0 = *(const bf16x8*)&Bs[wc +      l15][swzi(wc +      l15, q)];
        bf16x8 b1 = *(const bf16x8*)&Bs[wc + 16 + l15][swzi(wc + 16 + l15, q)];
        acc[0][0] = __builtin_amdgcn_mfma_f32_16x16x32_bf16(a0, b0, acc[0][0], 0, 0, 0);
        acc[0][1] = __builtin_amdgcn_mfma_f32_16x16x32_bf16(a0, b1, acc[0][1], 0, 0, 0);
        acc[1][0] = __builtin_amdgcn_mfma_f32_16x16x32_bf16(a1, b0, acc[1][0], 0, 0, 0);
        acc[1][1] = __builtin_amdgcn_mfma_f32_16x16x32_bf16(a1, b1, acc[1][1], 0, 0, 0);
        __syncthreads();
    }
    const int cq = lane >> 4, cc = lane & 15;
#pragma unroll
    for (int i = 0; i < 2; i++)
#pragma unroll
        for (int j = 0; j < 2; j++) {
#pragma unroll
            for (int rg = 0; rg < 4; rg++) {
                int row = m0 + wr + i * 16 + cq * 4 + rg;
                int col = n0 + wc + j * 16 + cc;
                float v = acc[i][j][rg];
                if (bias) v += bias[col];
                if (ACT == 1) v = v > 0.f ? v : 0.f;
                C[(long)row * ldc + col] = v;
            }
        }
}

// ---------------------------------------------------------------------------
// Helpers (unchanged)
// ---------------------------------------------------------------------------
__global__ void combine_bias(const float* a0, const float* b0,
                             const float* a1, const float* b1,
                             const float* a2, const float* b2,
                             float* o0, float* o1, float* o2)
{
    int i = blockIdx.x * 256 + threadIdx.x;
    o0[i] = a0[i] + b0[i];
    o1[i] = a1[i] + b1[i];
    o2[i] = a2[i] + b2[i];
}

__global__ void seq_major(const float* __restrict__ M, float* __restrict__ Mseq)
{
    int b = blockIdx.x;
    int s = b >> 8, n = b & 255;
    int t = threadIdx.x;
    Mseq[(long)b * 256 + t] = M[((long)n * 64 + s) * 256 + t];
}

// ---------------------------------------------------------------------------
// pack_w: V3 (8-wave) fragment layout (unchanged).
// ---------------------------------------------------------------------------
__global__ __launch_bounds__(256) void pack_w(
    const float* __restrict__ Wf, const float* __restrict__ Wb, const float* __restrict__ Wc,
    unsigned short* __restrict__ Pf, unsigned short* __restrict__ Pb, unsigned short* __restrict__ Pc)
{
    int chunk = blockIdx.x * 256 + threadIdx.x;      // 0..24575
    const float* W = (blockIdx.y == 0) ? Wf : ((blockIdx.y == 1) ? Wb : Wc);
    unsigned short* P = (blockIdx.y == 0) ? Pf : ((blockIdx.y == 1) ? Pb : Pc);
    int lane = chunk & 63;
    int kt   = (chunk >> 6) & 7;
    int f    = (chunk >> 9) % 6;
    int w    = chunk / 3072;
    int g = f >> 1, hh = f & 1;
    int c = lane & 15, q = lane >> 4;
    int col = g * 256 + w * 32 + hh * 16 + c;
    int k0  = kt * 32 + q * 8;
    unsigned int v[8];
#pragma unroll
    for (int j = 0; j < 8; j++) v[j] = f2b(W[(long)(k0 + j) * 768 + col]);
    uint4 o;
    o.x = v[0] | (v[1] << 16); o.y = v[2] | (v[3] << 16);
    o.z = v[4] | (v[5] << 16); o.w = v[6] | (v[7] << 16);
    *(uint4*)&P[(long)chunk * 8] = o;
}

__global__ void build_x(const float* __restrict__ values, const float* __restrict__ Mbuf,
                        const int* __restrict__ actions, const int* __restrict__ a0,
                        float* __restrict__ Xc, int t0)
{
    int m = blockIdx.x;
    int tl = m >> 8, n = m & 255;
    int t = t0 + tl;
    int c = threadIdx.x;
    float v;
    if (c < 64) {
        v = values[((long)t * 256 + n) * 64 + c];
    } else {
        int ap = (t == 0) ? a0[n] : actions[(long)(t - 1) * 256 + n];
        v = Mbuf[((long)n * 64 + ap) * 256 + (c - 64)];
    }
    Xc[(long)m * 320 + c] = v;
}

// ---------------------------------------------------------------------------
// Fused kernel: role-multiplexed. Roles share no barriers with each other's
// data (all inter-role deps are KERNEL-boundary ordered); ring buffers keep
// every intra-kernel reader/writer pair slot-disjoint.
// ---------------------------------------------------------------------------
struct GemmRole {
    const float* A; const float* B; const float* bias; float* C;
    int K; long lda; long ldb; long ldc; int act; int nblocks; int ntn;
};

union FusedLds {
    struct { unsigned short hbuf[2][16][264]; float gibuf[2][16 * 772]; } s;
    struct { unsigned short As[64][32]; unsigned short Bs[128][32]; } g;
    struct { unsigned short As2[2][64][32]; unsigned short Bs2[2][64][32]; } l;
};

// ---- scan role: EXACT v3 structure (8 waves, split-hh, fences, vmcnt(8)) ----
__device__ __forceinline__ void scan_role(FusedLds* L,
    const float* gi, const unsigned short* PK, const float* h_init,
    float* outp, float* h_state, int n0, int steps, int kgru, int d)
{
    auto& hbuf  = L->s.hbuf;
    auto& gibuf = L->s.gibuf;
    const int tid = threadIdx.x;
    const int w = tid >> 6, lane = tid & 63;
    const int q = lane >> 4, c = lane & 15, q8 = q << 3;
    const int wcol = w * 32;

    bf16x8 Bf[6][8];
#pragma unroll
    for (int f = 0; f < 6; f++)
#pragma unroll
        for (int kt = 0; kt < 8; kt++)
            Bf[f][kt] = *(const bf16x8*)&PK[(((long)(w * 6 + f) * 8 + kt) * 64 + lane) * 8];

    f32x4 hreg[2];
#pragma unroll
    for (int hh = 0; hh < 2; hh++)
#pragma unroll
        for (int rg = 0; rg < 4; rg++) {
            float v = 0.f;
            if (!kgru) v = h_init[(long)(n0 + q * 4 + rg) * 256 + wcol + hh * 16 + c];
            hreg[hh][rg] = v;
            hbuf[1][q * 4 + rg][wcol + hh * 16 + c] = f2b(v);
        }

    const int row0 = kgru ? (d ? 63 : 0) : 0;
    const long gstride = (kgru && d) ? -196608L : 196608L;
    const float* gsrc = gi + ((long)row0 * 256 + n0) * 768;
    float* optr[4];
    long ostride;
    if (kgru) {
        ostride = d ? -512L : 512L;
#pragma unroll
        for (int rg = 0; rg < 4; rg++)
            optr[rg] = outp + ((long)(n0 + q * 4 + rg) * 64 + row0) * 512 + d * 256 + wcol + c;
    } else {
        ostride = 65536L;
#pragma unroll
        for (int rg = 0; rg < 4; rg++)
            optr[rg] = outp + (long)(n0 + q * 4 + rg) * 256 + wcol + c;
    }

#pragma unroll
    for (int i = 0; i < 6; i++) {
        int idx = w * 6 + i;
        int r = idx / 3, ch = idx % 3;
        gload_lds16(gsrc + (long)r * 768 + ch * 256 + lane * 4,
                    &gibuf[0][r * 772 + ch * 256]);
    }
    __syncthreads();

    for (int s = 0; s < steps; s++) {
        const int cur = s & 1;
        if (s + 1 < steps) {
            const float* src = gsrc + gstride;
#pragma unroll
            for (int i = 0; i < 6; i++) {
                int idx = w * 6 + i;
                int r = idx / 3, ch = idx % 3;
                gload_lds16(src + (long)r * 768 + ch * 256 + lane * 4,
                            &gibuf[cur ^ 1][r * 772 + ch * 256]);
            }
        }
        gsrc += gstride;
        asm volatile("" ::: "memory");

        const unsigned short* hrd = &hbuf[cur ^ 1][0][0];
        const float* gp = &gibuf[cur][(q * 4) * 772 + wcol + c];
        unsigned short* hwr = &hbuf[cur][q * 4][wcol + c];

#pragma unroll
        for (int hh = 0; hh < 2; hh++) {
            f32x4 ar = (f32x4){0.f, 0.f, 0.f, 0.f};
            f32x4 az = (f32x4){0.f, 0.f, 0.f, 0.f};
            f32x4 an = (f32x4){0.f, 0.f, 0.f, 0.f};
#pragma unroll
            for (int kt = 0; kt < 8; kt++) {
                bf16x8 a = *(const bf16x8*)&hrd[c * 264 + kt * 32 + q8];
                ar = __builtin_amdgcn_mfma_f32_16x16x32_bf16(a, Bf[0 + hh][kt], ar, 0, 0, 0);
                az = __builtin_amdgcn_mfma_f32_16x16x32_bf16(a, Bf[2 + hh][kt], az, 0, 0, 0);
                an = __builtin_amdgcn_mfma_f32_16x16x32_bf16(a, Bf[4 + hh][kt], an, 0, 0, 0);
            }
#pragma unroll
            for (int rg = 0; rg < 4; rg++) {
                float gr = gp[rg * 772 +       hh * 16];
                float gz = gp[rg * 772 + 256 + hh * 16];
                float gn = gp[rg * 772 + 512 + hh * 16];
                float r  = __builtin_amdgcn_rcpf(1.f + __expf(-(gr + ar[rg])));
                float zg = __builtin_amdgcn_rcpf(1.f + __expf(-(gz + az[rg])));
                float nn = 1.f - 2.f * __builtin_amdgcn_rcpf(1.f + __expf(2.f * (gn + r * an[rg])));
                float hv = (1.f - zg) * nn + zg * hreg[hh][rg];
                hreg[hh][rg] = hv;
                hwr[rg * 264 + hh * 16] = f2b(hv);
                optr[rg][hh * 16] = hv;
            }
            asm volatile("" ::: "memory");
        }

#pragma unroll
        for (int rg = 0; rg < 4; rg++) optr[rg] += ostride;

        asm volatile("s_waitcnt vmcnt(8) lgkmcnt(0)" ::: "memory");
        __builtin_amdgcn_sched_barrier(0);
        __builtin_amdgcn_s_barrier();
        __builtin_amdgcn_sched_barrier(0);
    }

    if (!kgru) {
#pragma unroll
        for (int hh = 0; hh < 2; hh++)
#pragma unroll
            for (int rg = 0; rg < 4; rg++)
                h_state[(long)(n0 + q * 4 + rg) * 256 + wcol + hh * 16 + c] = hreg[hh][rg];
    }
}

// ---- gemm role: 512-thread 64x128 tile, B stored (K,N), swizzled LDS ----
__device__ __forceinline__ void gemm_role(FusedLds* L, const GemmRole& R, int rb)
{
    auto& As = L->g.As;
    auto& Bs = L->g.Bs;
    const int tid = threadIdx.x;
    const int lane = tid & 63, w = tid >> 6;
    const int mt = rb / R.ntn, nt = rb % R.ntn;
    const long m0 = (long)mt * 64, n0 = (long)nt * 128;
    const int wr = (w >> 2) * 32, wc = (w & 3) * 32;

    f32x4 acc[2][2];
#pragma unroll
    for (int i = 0; i < 2; i++)
#pragma unroll
        for (int j = 0; j < 2; j++) acc[i][j] = (f32x4){0.f, 0.f, 0.f, 0.f};

    for (int k0 = 0; k0 < R.K; k0 += 32) {
        {   // A: 64 x 32, 512 thr x 4 floats (8B writes, within-granule)
            const int r = tid >> 3, ck = (tid & 7) << 2;
            const float* s = R.A + (m0 + r) * R.lda + k0 + ck;
            float4 v = *(const float4*)s;
            unsigned short* dp = &As[r][swzi(r, ck >> 3) + (ck & 7)];
            dp[0] = f2b(v.x); dp[1] = f2b(v.y); dp[2] = f2b(v.z); dp[3] = f2b(v.w);
        }
        {   // B: 32 x 128 scatter-transpose (2B writes, swizzled)
            const int kk = tid >> 4, cn = (tid & 15) << 3;
            const float* s = R.B + (long)(k0 + kk) * R.ldb + n0 + cn;
            float4 v0 = *(const float4*)s, v1 = *(const float4*)(s + 4);
            const int sc = swzi(cn, kk >> 3) + (kk & 7);   // rows cn..cn+7 share row>>3
            Bs[cn + 0][sc] = f2b(v0.x); Bs[cn + 1][sc] = f2b(v0.y);
            Bs[cn + 2][sc] = f2b(v0.z); Bs[cn + 3][sc] = f2b(v0.w);
            Bs[cn + 4][sc] = f2b(v1.x); Bs[cn + 5][sc] = f2b(v1.y);
            Bs[cn + 6][sc] = f2b(v1.z); Bs[cn + 7][sc] = f2b(v1.w);
        }
        __syncthreads();
        const int l15 = lane & 15, q = lane >> 4;
        bf16x8 a0 = *(const bf16x8*)&As[wr +      l15][swzi(wr +      l15, q)];
        bf16x8 a1 = *(const bf16x8*)&As[wr + 16 + l15][swzi(wr + 16 + l15, q)];
        bf16x8 b0 = *(const bf16x8*)&Bs[wc +      l15][swzi(wc +      l15, q)];
        bf16x8 b1 = *(const bf16x8*)&Bs[wc + 16 + l15][swzi(wc + 16 + l15, q)];
        acc[0][0] = __builtin_amdgcn_mfma_f32_16x16x32_bf16(a0, b0, acc[0][0], 0, 0, 0);
        acc[0][1] = __builtin_amdgcn_mfma_f32_16x16x32_bf16(a0, b1, acc[0][1], 0, 0, 0);
        acc[1][0] = __builtin_amdgcn_mfma_f32_16x16x32_bf16(a1, b0, acc[1][0], 0, 0, 0);
        acc[1][1] = __builtin_amdgcn_mfma_f32_16x16x32_bf16(a1, b1, acc[1][1], 0, 0, 0);
        __syncthreads();
    }
    const int cq = lane >> 4, cc = lane & 15;
#pragma unroll
    for (int i = 0; i < 2; i++)
#pragma unroll
        for (int j = 0; j < 2; j++) {
#pragma unroll
            for (int rg = 0; rg < 4; rg++) {
                long row = m0 + wr + i * 16 + cq * 4 + rg;
                long col = n0 + wc + j * 16 + cc;
                float v = acc[i][j][rg];
                if (R.bias) v += R.bias[col];
                if (R.act == 1) v = v > 0.f ? v : 0.f;
                R.C[row * R.ldc + col] = v;
            }
        }
}

// ---- logits role: dual-z 64x64x512 GEMM (threads 0-255: z=2rb, 256-511:
// z=2rb+1; both halves execute IDENTICAL barrier sequences). ----
__device__ __forceinline__ void logits_role(FusedLds* L, int rb,
    const float* Qs, const float* Kb, float* Lout)
{
    auto& As = L->l.As2;
    auto& Bs = L->l.Bs2;
    const int tid = threadIdx.x;
    const int half = tid >> 8, htid = tid & 255;
    const int z = rb * 2 + half;
    const float* A = Qs + (long)z * 512;     // rows stride 131072 (t-local)
    const float* B = Kb + (long)z * 32768;   // K[n=z], rows stride 512
    float* C = Lout + (long)z * 64;          // rows stride 16384
    const int lane = htid & 63, w4 = htid >> 6;
    const int wr = (w4 >> 1) * 32, wc = (w4 & 1) * 32;

    f32x4 acc[2][2];
#pragma unroll
    for (int i = 0; i < 2; i++)
#pragma unroll
        for (int j = 0; j < 2; j++) acc[i][j] = (f32x4){0.f, 0.f, 0.f, 0.f};

    for (int k0 = 0; k0 < 512; k0 += 32) {
        const int r = htid >> 2, ck = (htid & 3) << 3;
        {
            const float* s = A + (long)r * 131072 + k0 + ck;
            float4 v0 = *(const float4*)s, v1 = *(const float4*)(s + 4);
            unsigned short* d = &As[half][r][swzi(r, ck >> 3)];
            d[0] = f2b(v0.x); d[1] = f2b(v0.y); d[2] = f2b(v0.z); d[3] = f2b(v0.w);
            d[4] = f2b(v1.x); d[5] = f2b(v1.y); d[6] = f2b(v1.z); d[7] = f2b(v1.w);
        }
        {
            const float* s = B + (long)r * 512 + k0 + ck;
            float4 v0 = *(const float4*)s, v1 = *(const float4*)(s + 4);
            unsigned short* d = &Bs[half][r][swzi(r, ck >> 3)];
            d[0] = f2b(v0.x); d[1] = f2b(v0.y); d[2] = f2b(v0.z); d[3] = f2b(v0.w);
            d[4] = f2b(v1.x); d[5] = f2b(v1.y); d[6] = f2b(v1.z); d[7] = f2b(v1.w);
        }
        __syncthreads();
        const int l15 = lane & 15, q = lane >> 4;
        bf16x8 a0 = *(const bf16x8*)&As[half][wr +      l15][swzi(wr +      l15, q)];
        bf16x8 a1 = *(const bf16x8*)&As[half][wr + 16 + l15][swzi(wr + 16 + l15, q)];
        bf16x8 b0 = *(const bf16x8*)&Bs[half][wc +      l15][swzi(wc +      l15, q)];
        bf16x8 b1 = *(const bf16x8*)&Bs[half][wc + 16 + l15][swzi(wc + 16 + l15, q)];
        acc[0][0] = __builtin_amdgcn_mfma_f32_16x16x32_bf16(a0, b0, acc[0][0], 0, 0, 0);
        acc[0][1] = __builtin_amdgcn_mfma_f32_16x16x32_bf16(a0, b1, acc[0][1], 0, 0, 0);
        acc[1][0] = __builtin_amdgcn_mfma_f32_16x16x32_bf16(a1, b0, acc[1][0], 0, 0, 0);
        acc[1][1] = __builtin_amdgcn_mfma_f32_16x16x32_bf16(a1, b1, acc[1][1], 0, 0, 0);
        __syncthreads();
    }
    const int cq = lane >> 4, cc = lane & 15;
#pragma unroll
    for (int i = 0; i < 2; i++)
#pragma unroll
        for (int j = 0; j < 2; j++) {
#pragma unroll
            for (int rg = 0; rg < 4; rg++)
                C[(long)(wr + i * 16 + cq * 4 + rg) * 16384 + wc + j * 16 + cc] = acc[i][j][rg];
        }
}

// ---- epilogue role: per warp, one (t,n); no barriers ----
__device__ __forceinline__ void epi_role(int rb,
    const float* Hall, const float* Lc, const int* actions,
    const float* critic_W, const float* critic_b, float* out, int t0)
{
    const int w = threadIdx.x >> 6, j = threadIdx.x & 63;
    const int m = rb * 8 + w;
    const int tl = m >> 8, n = m & 255;
    const int t = t0 + tl;
    long o = ((long)t * 256 + n) * 322;
    const float* h = Hall + (long)m * 256;
    float part = 0.f;
#pragma unroll
    for (int i = 0; i < 4; i++) {
        float hv = h[j + 64 * i];
        out[o + 2 + j + 64 * i] = hv;
        part += hv * critic_W[j + 64 * i];
    }
    for (int off = 32; off > 0; off >>= 1) part += __shfl_down(part, off);
    if (j == 0) {
        out[o]     = (float)actions[(long)t * 256 + n];
        out[o + 1] = part + critic_b[0];
    }
    float x = Lc[(long)m * 64 + j];
    float mx = x;
    for (int off = 32; off > 0; off >>= 1) mx = fmaxf(mx, __shfl_down(mx, off));
    mx = __shfl(mx, 0);
    float e = __expf(x - mx);
    float ssum = e;
    for (int off = 32; off > 0; off >>= 1) ssum += __shfl_down(ssum, off);
    ssum = __shfl(ssum, 0);
    out[o + 258 + j] = e / ssum;
}

// ---- build_x role ----
__device__ __forceinline__ void bx_role(int rb,
    const float* values, const float* Mbuf, const int* actions, const int* a0,
    float* Xd, int t0)
{
    const int tid = threadIdx.x;
    if (tid >= 320) return;      // no barriers in this role — safe
    for (int rr = 0; rr < 128; rr++) {
        int m = rb * 128 + rr;
        int tl = m >> 8, n = m & 255;
        int t = t0 + tl;
        float v;
        if (tid < 64) {
            v = values[((long)t * 256 + n) * 64 + tid];
        } else {
            int ap = (t == 0) ? a0[n] : actions[(long)(t - 1) * 256 + n];
            v = Mbuf[((long)n * 64 + ap) * 256 + (tid - 64)];
        }
        Xd[(long)m * 320 + tid] = v;
    }
}

__global__ __launch_bounds__(512, 2) void fused_k(
    const float* sc_gi, const unsigned short* sc_PK, const float* sc_hinit,
    float* sc_out, float* sc_hstate,
    int kgru_nblk, const float* kg_gi0, const float* kg_gi1,
    const unsigned short* kg_PK0, const unsigned short* kg_PK1, float* kg_out,
    GemmRole g0, GemmRole g1, GemmRole g2, GemmRole g3,
    int lg_nblk, const float* lg_Q, const float* lg_K, float* lg_L,
    int ep_nblk, const float* ep_Hall, const float* ep_L, int ep_t0,
    int bx_nblk, const float* values, const float* Mbuf,
    const int* actions, const int* a0, float* bx_dst, int bx_t0,
    const float* critic_W, const float* critic_b, float* out)
{
    __shared__ __align__(16) FusedLds L;
    int b = blockIdx.x;
    if (b < 16) {
        scan_role(&L, sc_gi, sc_PK, sc_hinit, sc_out, sc_hstate, b * 16, TCHUNK, 0, 0);
        return;
    }
    b -= 16;
    if (b < kgru_nblk) {
        int d = b >> 4, n0 = (b & 15) * 16;
        scan_role(&L, d ? kg_gi1 : kg_gi0, d ? kg_PK1 : kg_PK0, nullptr,
                  kg_out, nullptr, n0, 64, 1, d);
        return;
    }
    b -= kgru_nblk;
    if (b < g0.nblocks) { gemm_role(&L, g0, b); return; }
    b -= g0.nblocks;
    if (b < g1.nblocks) { gemm_role(&L, g1, b); return; }
    b -= g1.nblocks;
    if (b < g2.nblocks) { gemm_role(&L, g2, b); return; }
    b -= g2.nblocks;
    if (b < g3.nblocks) { gemm_role(&L, g3, b); return; }
    b -= g3.nblocks;
    if (b < lg_nblk) { logits_role(&L, b, lg_Q, lg_K, lg_L); return; }
    b -= lg_nblk;
    if (b < ep_nblk) { epi_role(b, ep_Hall, ep_L, actions, critic_W, critic_b, out, ep_t0); return; }
    b -= ep_nblk;
    if (b < bx_nblk) bx_role(b, values, Mbuf, actions, a0, bx_dst, bx_t0);
}

// ---------------------------------------------------------------------------
// Epilogue kernel (tail use)
// ---------------------------------------------------------------------------
__global__ __launch_bounds__(64) void epilogue_k(
    const float* __restrict__ Hallc, const float* __restrict__ Lc,
    const int* __restrict__ actions,
    const float* __restrict__ critic_W, const float* __restrict__ critic_b,
    float* __restrict__ out, int t0)
{
    int m = blockIdx.x;
    int tl = m >> 8, n = m & 255;
    int t = t0 + tl;
    int j = threadIdx.x;
    long o = ((long)t * 256 + n) * 322;
    const float* h = Hallc + (long)m * 256;
    float part = 0.f;
#pragma unroll
    for (int i = 0; i < 4; i++) {
        float hv = h[j + 64 * i];
        out[o + 2 + j + 64 * i] = hv;
        part += hv * critic_W[j + 64 * i];
    }
    for (int off = 32; off > 0; off >>= 1) part += __shfl_down(part, off);
    if (j == 0) {
        out[o]     = (float)actions[(long)t * 256 + n];
        out[o + 1] = part + critic_b[0];
    }
    float x = Lc[(long)m * 64 + j];
    float mx = x;
    for (int off = 32; off > 0; off >>= 1) mx = fmaxf(mx, __shfl_down(mx, off));
    mx = __shfl(mx, 0);
    float e = __expf(x - mx);
    float ssum = e;
    for (int off = 32; off > 0; off >>= 1) ssum += __shfl_down(ssum, off);
    ssum = __shfl(ssum, 0);
    out[o + 258 + j] = e / ssum;
}

// ---------------------------------------------------------------------------
extern "C" void kernel_launch(void* const* d_in, const int* in_sizes, int n_in,
                              void* d_out, int out_size, void* d_ws, size_t ws_size,
                              hipStream_t stream)
{
    const float* values   = (const float*)d_in[0];
    const float* mdp      = (const float*)d_in[1];
    const int*   actions  = (const int*)  d_in[2];
    const int*   a0       = (const int*)  d_in[3];
    const float* h0       = (const float*)d_in[4];
    const float* emb_W    = (const float*)d_in[5];
    const float* emb_b    = (const float*)d_in[6];
    const float* gfw_Wih  = (const float*)d_in[7];
    const float* gfw_Whh  = (const float*)d_in[8];
    const float* gfw_bih  = (const float*)d_in[9];
    const float* gfw_bhh  = (const float*)d_in[10];
    const float* gbw_Wih  = (const float*)d_in[11];
    const float* gbw_Whh  = (const float*)d_in[12];
    const float* gbw_bih  = (const float*)d_in[13];
    const float* gbw_bhh  = (const float*)d_in[14];
    const float* f0_W     = (const float*)d_in[15];
    const float* f0_b     = (const float*)d_in[16];
    const float* f1_W     = (const float*)d_in[17];
    const float* f1_b     = (const float*)d_in[18];
    const float* cell_Wih = (const float*)d_in[19];
    const float* cell_Whh = (const float*)d_in[20];
    const float* cell_bih = (const float*)d_in[21];
    const float* cell_bhh = (const float*)d_in[22];
    const float* critic_W = (const float*)d_in[23];
    const float* critic_b = (const float*)d_in[24];
    const float* qg_W     = (const float*)d_in[25];
    const float* qg_b     = (const float*)d_in[26];
    float* out = (float*)d_out;

    char* base = (char*)d_ws;
    size_t off = 0;
    auto alloc = [&](size_t nf) -> float* {
        float* p = (float*)(base + off);
        off += nf * sizeof(float);
        off = (off + 255) & ~(size_t)255;
        return p;
    };
    float* Mbuf   = alloc(16384ull * 256);
    float* Mseq   = alloc(16384ull * 256);   // aliased as Hallr[2] after prologue
    float* gfA    = alloc(16384ull * 768);   // aliased as Qr[0] after fused(0)
    float* gbA    = alloc(16384ull * 768);   // aliased as Qr[1] after fused(0)
    float* Kbuf   = alloc(256ull * 64 * 512);
    float* PKf    = alloc(98304);
    float* PKb    = alloc(98304);
    float* PKc    = alloc(98304);
    float* hstate = alloc(256ull * 256);
    float* Xr[2]    = { alloc(16384ull * 320), alloc(16384ull * 320) };
    float* X0r[2]   = { alloc(16384ull * 256), alloc(16384ull * 256) };
    float* X1r[2]   = { alloc(16384ull * 256), alloc(16384ull * 256) };
    float* GIr[2]   = { alloc(16384ull * 768), alloc(16384ull * 768) };
    float* Hallr[4] = { alloc(16384ull * 256), alloc(16384ull * 256),
                        Mseq, alloc(16384ull * 256) };
    float* Qr[2]  = { gfA, gbA };            // 16384x512 each; gfA/gbA dead after fused(0)
    float* Lr[2]  = { alloc(16384ull * 64), alloc(16384ull * 64) };
    float* bias_f = alloc(768);
    float* bias_b = alloc(768);
    float* bias_c = alloc(768);
    (void)ws_size; (void)in_sizes; (void)n_in; (void)out_size;

    dim3 blk(256);

    // ---- Phase 1: embeddings, gate-input GEMMs, weight packing ----
    gemm_f32<false, 0><<<dim3(4, 256, 1), blk, 0, stream>>>(
        mdp, 128, 0, emb_W, 256, 0, emb_b, Mbuf, 256, 0, 16384, 256, 128);
    seq_major<<<dim3(16384), blk, 0, stream>>>(Mbuf, Mseq);
    pack_w<<<dim3(96, 3, 1), blk, 0, stream>>>(
        gfw_Whh, gbw_Whh, cell_Whh,
        (unsigned short*)PKf, (unsigned short*)PKb, (unsigned short*)PKc);
    combine_bias<<<dim3(3), blk, 0, stream>>>(gfw_bih, gfw_bhh, gbw_bih, gbw_bhh,
                                              cell_bih, cell_bhh, bias_f, bias_b, bias_c);
    gemm_f32<false, 0><<<dim3(12, 256, 1), blk, 0, stream>>>(
        Mseq, 256, 0, gfw_Wih, 768, 0, bias_f, gfA, 768, 0, 16384, 768, 256);
    gemm_f32<false, 0><<<dim3(12, 256, 1), blk, 0, stream>>>(
        Mseq, 256, 0, gbw_Wih, 768, 0, bias_b, gbA, 768, 0, 16384, 768, 256);

    // ---- Pipeline priming (x-path for chunks 0..3 partial) ----
    build_x<<<dim3(16384), dim3(320), 0, stream>>>(values, Mbuf, actions, a0, Xr[0], 0);
    gemm_f32<false, 1><<<dim3(4, 256, 1), blk, 0, stream>>>(
        Xr[0], 320, 0, f0_W, 256, 0, f0_b, X0r[0], 256, 0, 16384, 256, 320);
    build_x<<<dim3(16384), dim3(320), 0, stream>>>(values, Mbuf, actions, a0, Xr[1], 64);
    gemm_f32<false, 1><<<dim3(4, 256, 1), blk, 0, stream>>>(
        Xr[1], 320, 0, f0_W, 256, 0, f0_b, X0r[1], 256, 0, 16384, 256, 320);
    gemm_f32<false, 1><<<dim3(4, 256, 1), blk, 0, stream>>>(
        X0r[0], 256, 0, f1_W, 256, 0, f1_b, X1r[0], 256, 0, 16384, 256, 256);
    build_x<<<dim3(16384), dim3(320), 0, stream>>>(values, Mbuf, actions, a0, Xr[0], 128);
    gemm_f32<false, 1><<<dim3(4, 256, 1), blk, 0, stream>>>(
        Xr[0], 320, 0, f0_W, 256, 0, f0_b, X0r[0], 256, 0, 16384, 256, 320);
    gemm_f32<false, 1><<<dim3(4, 256, 1), blk, 0, stream>>>(
        X0r[1], 256, 0, f1_W, 256, 0, f1_b, X1r[1], 256, 0, 16384, 256, 256);
    build_x<<<dim3(16384), dim3(320), 0, stream>>>(values, Mbuf, actions, a0, Xr[1], 192);
    gemm_f32<false, 0><<<dim3(12, 256, 1), blk, 0, stream>>>(
        X1r[0], 256, 0, cell_Wih, 768, 0, bias_c, GIr[0], 768, 0, 16384, 768, 256);

    // ---- Fused pipeline (staggered roles):
    //   fused(c) = scan(c) | kgru(c==0) | f0(c+3) | f1(c+2) | GI(c+1)
    //            | qg(c-1) | logits(c-2) | epi(c-3) | bx(c+4)
    for (int c = 0; c < NCHUNK; c++) {
        GemmRole g0{}, g1{}, g2{}, g3{};
        if (c <= 4) g0 = GemmRole{ Xr[(c + 1) & 1], f0_W, f0_b, X0r[(c + 1) & 1],
                                   320, 320, 256, 256, 1, 512, 2 };
        if (c <= 5) g1 = GemmRole{ X0r[c & 1], f1_W, f1_b, X1r[c & 1],
                                   256, 256, 256, 256, 1, 512, 2 };
        if (c <= 6) g2 = GemmRole{ X1r[(c + 1) & 1], cell_Wih, bias_c, GIr[(c + 1) & 1],
                                   256, 256, 768, 768, 0, 1536, 6 };
        if (c >= 1) g3 = GemmRole{ Hallr[(c - 1) & 3], qg_W, qg_b, Qr[(c - 1) & 1],
                                   256, 256, 512, 512, 0, 1024, 4 };
        int kgn = (c == 0) ? 32 : 0;
        int lgn = (c >= 2) ? 128 : 0;
        int epn = (c >= 3) ? 2048 : 0;
        int bxn = (c <= 3) ? 128 : 0;
        int total = 16 + kgn + g0.nblocks + g1.nblocks + g2.nblocks + g3.nblocks
                    + lgn + epn + bxn;

        fused_k<<<dim3(total), dim3(512), 0, stream>>>(
            GIr[c & 1], (const unsigned short*)PKc, (c == 0) ? h0 : (const float*)hstate,
            Hallr[c & 3], hstate,
            kgn, gfA, gbA, (const unsigned short*)PKf, (const unsigned short*)PKb, Kbuf,
            g0, g1, g2, g3,
            lgn, Qr[(c - 2) & 1], Kbuf, Lr[(c - 2) & 1],
            epn, Hallr[(c - 3) & 3], Lr[(c - 3) & 1], (c - 3) * 64,
            bxn, values, Mbuf, actions, a0, Xr[c & 1], (c + 4) * 64,
            critic_W, critic_b, out);
    }

    // ---- Tail: drain the staggered pipeline (chunks 5,6,7) ----
    epilogue_k<<<dim3(16384), dim3(64), 0, stream>>>(
        Hallr[1], Lr[1], actions, critic_W, critic_b, out, 5 * 64);
    gemm_f32<false, 0><<<dim3(8, 256, 1), blk, 0, stream>>>(
        Hallr[3], 256, 0, qg_W, 512, 0, qg_b, Qr[1], 512, 0, 16384, 512, 256);
    gemm_f32<true, 0><<<dim3(1, 1, 256), blk, 0, stream>>>(
        Qr[0], 131072, 512, Kbuf, 512, 32768, nullptr, Lr[0], 16384, 64, 64, 64, 512);
    epilogue_k<<<dim3(16384), dim3(64), 0, stream>>>(
        Hallr[2], Lr[0], actions, critic_W, critic_b, out, 6 * 64);
    gemm_f32<true, 0><<<dim3(1, 1, 256), blk, 0, stream>>>(
        Qr[1], 131072, 512, Kbuf, 512, 32768, nullptr, Lr[1], 16384, 64, 64, 64, 512);
    epilogue_k<<<dim3(16384), dim3(64), 0, stream>>>(
        Hallr[3], Lr[1], actions, critic_W, critic_b, out, 7 * 64);
}